// Round 13
// baseline (420.168 us; speedup 1.0000x reference)
//
#include <hip/hip_runtime.h>

#define N_NODES 100000
#define N_EDGES 1600000
#define D 128
#define NBUCK 196         // ceil(N_NODES / 512), bucket = dst >> 9
#define CAP 10240         // ebuf slab capacity per bucket; mean 8163, sigma~90 -> +23 sigma
#define PCAP 12288        // csr slab capacity per bucket (%4-padded); max = CAP + 3*512 = 11776
#define NBLK32 3125       // N_NODES / 32 row-blocks (exact)

typedef __attribute__((ext_vector_type(8))) short bf16x8;
typedef __attribute__((ext_vector_type(4))) float f32x4;
typedef unsigned long long u64;

__device__ __forceinline__ float b2f_lo(unsigned int u) {
    return __builtin_bit_cast(float, u << 16);
}
__device__ __forceinline__ float b2f_hi(unsigned int u) {
    return __builtin_bit_cast(float, u & 0xFFFF0000u);
}
__device__ __forceinline__ unsigned short f2b(float f) {
    unsigned int u = __builtin_bit_cast(unsigned int, f);
    u += 0x7FFFu + ((u >> 16) & 1u);
    return (unsigned short)(u >> 16);
}

// ---------------- prep (+ fused bin): weights -> fragment order, x -> bf16, edge binning ----------------
// bin is fused as blocks [12884, 13666): it only needs bcur zeroed, which the
// hipMemsetAsync before this dispatch guarantees. Saves one dispatch gap.

__global__ __launch_bounds__(256) void prep_kernel(
    const float* __restrict__ x, unsigned short* __restrict__ xb,
    const float* __restrict__ W0, const float* __restrict__ W1_, const float* __restrict__ W2_,
    const float* __restrict__ W3, const float* __restrict__ W4, const float* __restrict__ W5,
    unsigned short* __restrict__ T0, unsigned short* __restrict__ T1_,
    unsigned short* __restrict__ T2_, unsigned short* __restrict__ T3,
    unsigned short* __restrict__ T4, unsigned short* __restrict__ T5,
    const int* __restrict__ src, const int* __restrict__ dst,
    int* __restrict__ bcur, unsigned int* __restrict__ ebuf,
    uint4* __restrict__ xs0) {
    __shared__ int h[NBUCK];
    __shared__ int hbase[NBUCK];
    int blk = blockIdx.x;
    int tid = threadIdx.x;
    if (blk < 384) {
        const float* W;
        unsigned short* T;
        switch (blk >> 6) {
            case 0: W = W0; T = T0; break;
            case 1: W = W1_; T = T1_; break;
            case 2: W = W2_; T = T2_; break;
            case 3: W = W3; T = T3; break;
            case 4: W = W4; T = T4; break;
            default: W = W5; T = T5; break;
        }
        int i = (blk & 63) * 256 + tid;           // 0..16383, i = k*128 + n
        int k = i >> 7, n = i & 127;
        int nt = n >> 4, mr = n & 15;
        int kc = k >> 5, rem = k & 31, quad = rem >> 3, j = rem & 7;
        T[(nt * 4 + kc) * 512 + quad * 128 + mr * 8 + j] = f2b(W[i]);
    } else if (blk < 12884) {
        int i = (blk - 384) * 256 + tid;          // float4 chunks, 3,200,000 total
        if (i < 3200000) {
            float4 v = ((const float4*)x)[i];
            ushort4 o;
            o.x = f2b(v.x); o.y = f2b(v.y); o.z = f2b(v.z); o.w = f2b(v.w);
            ((ushort4*)xb)[i] = o;
        }
    } else if (blk < 13666) {
        // ---- bin: scatter edges into fixed-stride bucket slabs ----
        int b0 = blk - 12884;
        if (tid < NBUCK) h[tid] = 0;
        __syncthreads();
        int e0 = b0 * 2048;
        int myd[8], mys[8];
#pragma unroll
        for (int i = 0; i < 8; i++) {
            int e = e0 + tid + i * 256;
            int dv = (e < N_EDGES) ? dst[e] : -1;
            myd[i] = dv;
            mys[i] = (e < N_EDGES) ? src[e] : 0;
            if (dv >= 0) atomicAdd(&h[dv >> 9], 1);
        }
        __syncthreads();
        if (tid < NBUCK) {
            int c = h[tid];
            hbase[tid] = (c > 0) ? (tid * CAP + atomicAdd(&bcur[tid], c)) : 0;
            h[tid] = 0;
        }
        __syncthreads();
#pragma unroll
        for (int i = 0; i < 8; i++) {
            int dv = myd[i];
            if (dv >= 0) {
                int b = dv >> 9;
                int p = hbase[b] + atomicAdd(&h[b], 1);
                if (p < (b + 1) * CAP)
                    ebuf[p] = ((unsigned int)(dv & 511) << 22) | (unsigned int)mys[i];
            }
        }
    } else {
        if (tid < 16) {
            uint4 z = {0u, 0u, 0u, 0u};
            xs0[tid] = z;    // zero sentinel row xb[N_NODES]
        }
    }
}

// ---------------- per-bucket CSR: hist -> %4-padded scan -> off/offe -> scatter -> pads ----------------
// 512-node buckets, 196 blocks (was 98x1024 on 256 CUs -> 62% of CUs idle).

__global__ __launch_bounds__(512) void bucket_all_kernel(const unsigned int* __restrict__ ebuf,
                                                         const int* __restrict__ bcur,
                                                         int* __restrict__ off,
                                                         int* __restrict__ offe,
                                                         int* __restrict__ csr) {
    __shared__ int hist[512];
    __shared__ int sc[512];
    __shared__ int cnt[512];
    int b = blockIdx.x, tid = threadIdx.x;
    int nE = bcur[b]; if (nE > CAP) nE = CAP;
    int base = b * PCAP;
    const unsigned int* slab = ebuf + (size_t)b * CAP;
    hist[tid] = 0;
    cnt[tid] = 0;
    __syncthreads();
    for (int i = tid; i < nE; i += 512)
        atomicAdd(&hist[slab[i] >> 22], 1);
    __syncthreads();
    int node = b * 512 + tid;
    int d = hist[tid];
    int dp = (node < N_NODES) ? ((d + 3) & ~3) : 0;
    sc[tid] = dp;
    __syncthreads();
#pragma unroll
    for (int s = 1; s < 512; s <<= 1) {
        int t = (tid >= s) ? sc[tid - s] : 0;
        __syncthreads();
        sc[tid] += t;
        __syncthreads();
    }
    int excl = sc[tid] - dp;
    sc[tid] = excl;
    if (node < N_NODES) {
        off[node] = base + excl;
        offe[node] = base + excl + dp;
    }
    __syncthreads();
    for (int i = tid; i < nE; i += 512) {
        unsigned int e = slab[i];
        int dd = e >> 22;
        int pos = sc[dd] + atomicAdd(&cnt[dd], 1);
        csr[base + pos] = (int)(e & 0x3FFFFFu);
    }
    for (int j = d; j < dp; j++) csr[base + excl + j] = N_NODES;  // <=3 pads/node
}

// ---------------- aggregation: t[i] = x[i] + sum_{j in N_in(i)} x[j] ----------------
// Gather: R8-verified. Store: P in MFMA-fragment order (R11-verified).
// `nbase` param: each layer runs as TWO half-grid dispatches (~30us each) so the
// rocprof top-5 cutoff drops below mlp/prep/bucket_all -- diagnostic round.

__global__ __launch_bounds__(256) void agg_bf16(const unsigned int* __restrict__ xb,
                                                const int* __restrict__ off,
                                                const int* __restrict__ offe,
                                                const int* __restrict__ csr,
                                                unsigned int* __restrict__ Pf,
                                                int nbase) {
    int node = nbase + blockIdx.x * 4 + (threadIdx.x >> 6);
    int lane = threadIdx.x & 63;
    unsigned int v = xb[(size_t)node * 64 + lane];
    float ax = b2f_lo(v), ay = b2f_hi(v);
    int k = off[node], e = offe[node];
    for (; k + 16 <= e; k += 16) {
        int idx[16];
        unsigned int g[16];
#pragma unroll
        for (int i = 0; i < 16; i++) idx[i] = csr[k + i];
#pragma unroll
        for (int i = 0; i < 16; i++) g[i] = xb[(size_t)idx[i] * 64 + lane];
#pragma unroll
        for (int i = 0; i < 16; i++) { ax += b2f_lo(g[i]); ay += b2f_hi(g[i]); }
    }
    if (k + 8 <= e) {
        int idx[8];
        unsigned int g[8];
#pragma unroll
        for (int i = 0; i < 8; i++) idx[i] = csr[k + i];
#pragma unroll
        for (int i = 0; i < 8; i++) g[i] = xb[(size_t)idx[i] * 64 + lane];
#pragma unroll
        for (int i = 0; i < 8; i++) { ax += b2f_lo(g[i]); ay += b2f_hi(g[i]); }
        k += 8;
    }
    if (k < e) {
        int idx[4];
        unsigned int g[4];
#pragma unroll
        for (int i = 0; i < 4; i++) idx[i] = csr[k + i];
#pragma unroll
        for (int i = 0; i < 4; i++) g[i] = xb[(size_t)idx[i] * 64 + lane];
#pragma unroll
        for (int i = 0; i < 4; i++) { ax += b2f_lo(g[i]); ay += b2f_hi(g[i]); }
    }
    unsigned int packed = (unsigned int)f2b(ax) | ((unsigned int)f2b(ay) << 16);
    int B = node >> 5, sblk = (node >> 4) & 1, mr = node & 15;
    size_t didx = ((size_t)(B * 8 + sblk * 4 + (lane >> 4)) * 64
                   + ((lane >> 2) & 3) * 16 + mr) * 4 + (lane & 3);
    Pf[didx] = packed;
}

// ---------------- fused MLP (unchanged from R12 for clean measurement) ----------------

template <bool OUT_F32>
__global__ __launch_bounds__(256) void mlp_mfma(const unsigned short* __restrict__ A,
                                                const unsigned short* __restrict__ W1f,
                                                const float* __restrict__ bias1,
                                                const unsigned short* __restrict__ W2f,
                                                const float* __restrict__ bias2,
                                                void* __restrict__ out) {
    __shared__ char smem[4 * 4480];
    int tid = threadIdx.x;
    int wave = tid >> 6, lane = tid & 63;
    int quad = lane >> 4, mr = lane & 15;
    int gw = blockIdx.x * 4 + wave;            // 0..6251 (6250 real)
    int gwc = (gw > 2 * NBLK32 - 1) ? (2 * NBLK32 - 1) : gw;
    int B = gwc >> 1, sh = gwc & 1;
    int m_base = gw * 16;                      // true base; >=N_NODES masks all stores

    unsigned short* ust = (unsigned short*)(smem + wave * 4480);

    // ---- GEMM1: u = relu(t @ W1 + b1); A-loads contiguous 1KB wave-reads ----
    bf16x8 a[4];
#pragma unroll
    for (int kc = 0; kc < 4; kc++)
        a[kc] = *(const bf16x8*)(A + ((size_t)(B * 8 + sh * 4 + kc) * 64 + lane) * 8);

    f32x4 acc[8];
#pragma unroll
    for (int nt = 0; nt < 8; nt++) acc[nt] = (f32x4)0.0f;
#pragma unroll
    for (int nt = 0; nt < 8; nt++) {
#pragma unroll
        for (int kc = 0; kc < 4; kc++) {
            bf16x8 b = *(const bf16x8*)(W1f + (nt * 4 + kc) * 512 + lane * 8);
            acc[nt] = __builtin_amdgcn_mfma_f32_16x16x32_bf16(a[kc], b, acc[nt], 0, 0, 0);
        }
    }
    // C layout: col(n) = mr, row = quad*4 + r
#pragma unroll
    for (int nt = 0; nt < 8; nt++) {
        float bv = bias1[nt * 16 + mr];
#pragma unroll
        for (int r = 0; r < 4; r++)
            ust[(quad * 4 + r) * 136 + nt * 16 + mr] = f2b(fmaxf(acc[nt][r] + bv, 0.0f));
    }

    // ---- GEMM2: y = relu(u @ W2 + b2) ----
#pragma unroll
    for (int kc = 0; kc < 4; kc++)
        a[kc] = *(const bf16x8*)&ust[mr * 136 + kc * 32 + quad * 8];
#pragma unroll
    for (int nt = 0; nt < 8; nt++) acc[nt] = (f32x4)0.0f;
#pragma unroll
    for (int nt = 0; nt < 8; nt++) {
#pragma unroll
        for (int kc = 0; kc < 4; kc++) {
            bf16x8 b = *(const bf16x8*)(W2f + (nt * 4 + kc) * 512 + lane * 8);
            acc[nt] = __builtin_amdgcn_mfma_f32_16x16x32_bf16(a[kc], b, acc[nt], 0, 0, 0);
        }
    }

    // ---- epilogue ----
    if (OUT_F32) {
        float* st = (float*)ust;                // 8 x 132 f32 = 4224 B per pass
        const int S = 132;
        float* op = (float*)out;
#pragma unroll
        for (int p = 0; p < 2; p++) {
#pragma unroll
            for (int nt = 0; nt < 8; nt++) {
                float bv = bias2[nt * 16 + mr];
#pragma unroll
                for (int r = 0; r < 4; r++) {
                    int row16 = quad * 4 + r;
                    if ((row16 >> 3) == p)
                        st[(row16 & 7) * S + nt * 16 + mr] = fmaxf(acc[nt][r] + bv, 0.0f);
                }
            }
#pragma unroll
            for (int it = 0; it < 4; it++) {
                int linear = lane + it * 64;
                int row = linear >> 5, col = (linear & 31) << 2;
                int gm = m_base + p * 8 + row;
                if (gm < N_NODES) {
                    float4 val = *(float4*)&st[row * S + col];
                    *(float4*)(op + (size_t)gm * D + col) = val;
                }
            }
        }
    } else {
        const int S = 136;
        unsigned short* op = (unsigned short*)out;
#pragma unroll
        for (int nt = 0; nt < 8; nt++) {
            float bv = bias2[nt * 16 + mr];
#pragma unroll
            for (int r = 0; r < 4; r++)
                ust[(quad * 4 + r) * S + nt * 16 + mr] = f2b(fmaxf(acc[nt][r] + bv, 0.0f));
        }
#pragma unroll
        for (int it = 0; it < 4; it++) {
            int linear = lane + it * 64;
            int row = linear >> 4, col = (linear & 15) << 3;
            int gm = m_base + row;
            if (gm < N_NODES) {
                uint4 val = *(uint4*)&ust[row * S + col];
                *(uint4*)(op + (size_t)gm * D + col) = val;
            }
        }
    }
}

// ---------------- launch ----------------

extern "C" void kernel_launch(void* const* d_in, const int* in_sizes, int n_in,
                              void* d_out, int out_size, void* d_ws, size_t ws_size,
                              hipStream_t stream) {
    const float* x = (const float*)d_in[0];
    const int* ei = (const int*)d_in[1];
    const int* srcv = ei;
    const int* dstv = ei + N_EDGES;
    const float* W1[3] = {(const float*)d_in[2], (const float*)d_in[6], (const float*)d_in[10]};
    const float* b1[3] = {(const float*)d_in[3], (const float*)d_in[7], (const float*)d_in[11]};
    const float* W2[3] = {(const float*)d_in[4], (const float*)d_in[8], (const float*)d_in[12]};
    const float* b2[3] = {(const float*)d_in[5], (const float*)d_in[9], (const float*)d_in[13]};

    // ws layout (high-water 52,248,832):
    char* ws = (char*)d_ws;
    int* off  = (int*)ws;                                    // N ints @ 0
    int* offe = (int*)(ws + 400000);                         // N ints
    unsigned short* Wt[6];                                   // 6 x 32KB @ 800,000 (fragment order)
    for (int i = 0; i < 6; i++) Wt[i] = (unsigned short*)(ws + 800000 + i * 32768);
    unsigned short* xb = (unsigned short*)(ws + 1048576);    // (N+1)*256 B row-major, sentinel row N
    unsigned short* P  = (unsigned short*)(ws + 26648832);   // N*256 B FRAGMENT ORDER, ends 52,248,832

    // d_out scratch (all reads complete before mlp<true> writes d_out):
    char* dob = (char*)d_out;
    int* bcur = (int*)(dob);                              // NBUCK ints (memset below)
    unsigned int* ebuf = (unsigned int*)(dob + 1048576);  // NBUCK*CAP u32 = 8.03MB, ends 9,076,736
    int* csr  = (int*)(dob + 10485760);                   // NBUCK*PCAP ints = 9.63MB, ends 20,119,552

    // --- zero bcur (graph-capture-safe; harness reset uses hipMemsetAsync too) ---
    hipMemsetAsync(bcur, 0, NBUCK * sizeof(int), stream);

    // --- prep (+fused bin): weights->frag order, x->bf16, edge binning, sentinel ---
    prep_kernel<<<13667, 256, 0, stream>>>(
        x, xb,
        W1[0], W2[0], W1[1], W2[1], W1[2], W2[2],
        Wt[0], Wt[1], Wt[2], Wt[3], Wt[4], Wt[5],
        srcv, dstv, bcur, ebuf,
        (uint4*)(xb + (size_t)N_NODES * D));

    // --- per-bucket CSR (196 x 512) ---
    bucket_all_kernel<<<NBUCK, 512, 0, stream>>>(ebuf, bcur, off, offe, csr);

    const int agg_half = 12500;                        // 2 halves/layer (diagnostic split)
    const int mlp_grid = 1563;                         // 4 waves/block, 16 rows/wave

    // layer 0
    agg_bf16<<<agg_half, 256, 0, stream>>>((const unsigned int*)xb, off, offe, csr, (unsigned int*)P, 0);
    agg_bf16<<<agg_half, 256, 0, stream>>>((const unsigned int*)xb, off, offe, csr, (unsigned int*)P, 50000);
    mlp_mfma<false><<<mlp_grid, 256, 0, stream>>>(P, Wt[0], b1[0], Wt[1], b2[0], xb);
    // layer 1
    agg_bf16<<<agg_half, 256, 0, stream>>>((const unsigned int*)xb, off, offe, csr, (unsigned int*)P, 0);
    agg_bf16<<<agg_half, 256, 0, stream>>>((const unsigned int*)xb, off, offe, csr, (unsigned int*)P, 50000);
    mlp_mfma<false><<<mlp_grid, 256, 0, stream>>>(P, Wt[2], b1[1], Wt[3], b2[1], xb);
    // layer 2
    agg_bf16<<<agg_half, 256, 0, stream>>>((const unsigned int*)xb, off, offe, csr, (unsigned int*)P, 0);
    agg_bf16<<<agg_half, 256, 0, stream>>>((const unsigned int*)xb, off, offe, csr, (unsigned int*)P, 50000);
    mlp_mfma<true><<<mlp_grid, 256, 0, stream>>>(P, Wt[4], b1[2], Wt[5], b2[2], d_out);
}